// Round 5
// baseline (516.881 us; speedup 1.0000x reference)
//
#include <hip/hip_runtime.h>

#define B_TOT 4096
#define T_STEPS 512
#define IN 20
#define HID 51

typedef float f32x4 __attribute__((ext_vector_type(4)));
typedef short s16x8 __attribute__((ext_vector_type(8)));

__device__ __forceinline__ unsigned short f2bf(float f) {
    unsigned int u = __float_as_uint(f);
    return (unsigned short)((u + 0x7fffu + ((u >> 16) & 1u)) >> 16);
}
__device__ __forceinline__ float fast_rcp(float x) { return __builtin_amdgcn_rcpf(x); }

// 4 waves (1/SIMD), 4 tile-slots each (uniform, no divergence):
//   w0: {0,1,2, dead13} + x-stager A   w1: {3,4,5,6}
//   w2: {7,8,9, dead14} + x-stager B   w3: {10,11, mixed12, dead15}
// mixed tile 12: rows 0-3 = layer-2 gate rows (Wih2), rows 4-15 = units 48-50.
// Dead tiles have zero weights; their h==0 writes land in the zero pad K-region.
// A = weights, B = staged [x_t | h1_{t-1}] (N = 16 batches).
// D layout: col=lane&15=batch, reg = gate -> nonlinearity fully lane-local.
// Epilogue is STAGE-major across the 4 slots: 4-way ILP at every chain node.

__global__ __launch_bounds__(256, 1)
void lstm_fused(const float* __restrict__ x,
                const float* __restrict__ Wih1, const float* __restrict__ Whh1,
                const float* __restrict__ bih1, const float* __restrict__ bhh1,
                const float* __restrict__ Wih2, const float* __restrict__ Whh2,
                const float* __restrict__ bih2, const float* __restrict__ bhh2,
                const float* __restrict__ Wmu,  const float* __restrict__ bmu,
                const float* __restrict__ Wlv,  const float* __restrict__ blv,
                float* __restrict__ out)
{
    // B-operand staging, fragment order: [buf][ks][(((k>>3)&3)<<4)|batch][k&7]
    __shared__ __align__(16) unsigned short vA[2][3][64][8];

    const int tid  = threadIdx.x;
    const int lane = tid & 63;
    const int w    = tid >> 6;      // 0..3
    const int q    = lane >> 4;     // row-quad
    const int m    = lane & 15;
    const int bidx = blockIdx.x;

    // ---- slot -> tile table ----
    int tau[4];
    {
        int base = 3 * w + (w >= 2 ? 1 : 0);          // 0,3,7,10
        tau[0] = base; tau[1] = base + 1; tau[2] = base + 2;
        tau[3] = (w == 1) ? 6 : ((w == 0) ? 13 : ((w == 2) ? 14 : 15));
    }

    // ---- gather A-operand weight fragments: A[mrow=lane&15][k=q*8+j (+32ks)] ----
    s16x8 wf[4][3];
    f32x4 binit[4];
    #pragma unroll
    for (int s = 0; s < 4; ++s) {
        const int t = tau[s];
        #pragma unroll
        for (int ks = 0; ks < 3; ++ks) {
            s16x8 f;
            #pragma unroll
            for (int j = 0; j < 8; ++j) {
                int k = ks * 32 + (q << 3) + j;
                float v = 0.0f;
                if (t == 12) {
                    if (m < 4) {                      // layer-2 gate row m
                        if (k >= 32 && k < 32 + HID) v = Wih2[m * HID + (k - 32)];
                    } else {                          // units 48..50
                        int unit = 47 + (m >> 2), g = m & 3;
                        int row = g * HID + unit;
                        if (k < IN) v = Wih1[row * IN + k];
                        else if (k >= 32 && k < 32 + HID) v = Whh1[row * HID + (k - 32)];
                    }
                } else {
                    int unit = t * 4 + (m >> 2), g = m & 3;
                    if (unit < HID) {
                        int row = g * HID + unit;
                        if (k < IN) v = Wih1[row * IN + k];
                        else if (k >= 32 && k < 32 + HID) v = Whh1[row * HID + (k - 32)];
                    }
                }
                f[j] = (short)f2bf(v);
            }
            wf[s][ks] = f;
        }
        f32x4 bi = {0.f, 0.f, 0.f, 0.f};
        if (t == 12) {
            if (q == 0) {
                #pragma unroll
                for (int r = 0; r < 4; ++r) bi[r] = bih2[r] + bhh2[r];
            } else {
                int unit = 47 + q;
                #pragma unroll
                for (int r = 0; r < 4; ++r) bi[r] = bih1[r * HID + unit] + bhh1[r * HID + unit];
            }
        } else {
            int unit = t * 4 + q;
            if (unit < HID) {
                #pragma unroll
                for (int r = 0; r < 4; ++r) bi[r] = bih1[r * HID + unit] + bhh1[r * HID + unit];
            }
        }
        binit[s] = bi;
    }

    // ---- layer-2 recurrent adj (only w3, quad 0 lanes carry nonzero) ----
    const bool l2lane = (w == 3) && (q == 0);
    const float msk = l2lane ? 1.f : 0.f;
    float wadj[4];
    #pragma unroll
    for (int r = 0; r < 4; ++r) wadj[r] = l2lane ? Whh2[r] : 0.f;

    // ---- precomputed h-write LDS indices per slot ----
    int wch[4], wrow[4], wjj[4];
    #pragma unroll
    for (int s = 0; s < 4; ++s) {
        int t = tau[s];
        int u = (t == 12) ? ((q == 0) ? 51 : 47 + q) : t * 4 + q;  // q0-mixed -> pad col 51
        int k = 32 + u;
        wch[s] = k >> 5; wrow[s] = (((k >> 3) & 3) << 4) + m; wjj[s] = k & 7;
    }

    // ---- x stager: w0 lanes stage elems {lane, lane+64, lane+128}, w2 {lane+192, lane+256} ----
    const int ns = (w == 0) ? 3 : ((w == 2) ? 2 : 0);
    const int ebase = (w == 2) ? 192 : 0;
    const float* sp[3]; int srow[3], sj[3];
    #pragma unroll
    for (int i = 0; i < 3; ++i) {
        if (i < ns) {
            int e = ebase + i * 64 + lane;
            int b = e / IN, mm = e % IN;
            sp[i]   = x + ((size_t)(bidx * 16 + b) * T_STEPS) * IN + mm;
            srow[i] = ((mm >> 3) & 3) * 16 + b;
            sj[i]   = mm & 7;
        } else { sp[i] = x; srow[i] = 0; sj[i] = 0; }
    }

    // ---- zero-init both staging buffers (pads must be exact 0) ----
    {
        unsigned short* vz = &vA[0][0][0][0];
        for (int i = tid; i < 2 * 3 * 64 * 8; i += 256) vz[i] = 0;
    }
    __syncthreads();
    float xr[3] = {0.f, 0.f, 0.f};
    #pragma unroll
    for (int i = 0; i < 3; ++i) if (i < ns) {
        vA[0][0][srow[i]][sj[i]] = f2bf(sp[i][0]);   // x_0
        xr[i] = sp[i][IN];                           // prefetch x_1
    }
    __syncthreads();

    float c1[4] = {0.f, 0.f, 0.f, 0.f};
    float hm = 0.f, sum2 = 0.f;

    for (int t = 0; t < T_STEPS; ++t) {
        const int p  = t & 1;
        const int pn = p ^ 1;

        s16x8 bf0 = *(const s16x8*)&vA[p][0][lane][0];
        s16x8 bf1 = *(const s16x8*)&vA[p][1][lane][0];
        s16x8 bf2 = *(const s16x8*)&vA[p][2][lane][0];

        f32x4 acc[4];
        #pragma unroll
        for (int s = 0; s < 4; ++s) acc[s] = binit[s];
        #pragma unroll
        for (int r = 0; r < 4; ++r) acc[2][r] += wadj[r] * hm;   // L2 recurrent term

        #pragma unroll
        for (int s = 0; s < 4; ++s) acc[s] = __builtin_amdgcn_mfma_f32_16x16x32_bf16(wf[s][0], bf0, acc[s], 0, 0, 0);
        #pragma unroll
        for (int s = 0; s < 4; ++s) acc[s] = __builtin_amdgcn_mfma_f32_16x16x32_bf16(wf[s][1], bf1, acc[s], 0, 0, 0);
        #pragma unroll
        for (int s = 0; s < 4; ++s) acc[s] = __builtin_amdgcn_mfma_f32_16x16x32_bf16(wf[s][2], bf2, acc[s], 0, 0, 0);

        // ---- STAGE-major epilogue: 4-way ILP at every chain node ----
        float ei[4], ef[4], eg[4], eo[4];
        #pragma unroll
        for (int s = 0; s < 4; ++s) ei[s] = __expf(-acc[s][0]);
        #pragma unroll
        for (int s = 0; s < 4; ++s) ef[s] = __expf(-acc[s][1]);
        #pragma unroll
        for (int s = 0; s < 4; ++s) eg[s] = __expf(2.f * acc[s][2]);
        #pragma unroll
        for (int s = 0; s < 4; ++s) eo[s] = __expf(-acc[s][3]);
        float ri[4], rf[4], rg[4], ro[4];
        #pragma unroll
        for (int s = 0; s < 4; ++s) ri[s] = fast_rcp(1.f + ei[s]);
        #pragma unroll
        for (int s = 0; s < 4; ++s) rf[s] = fast_rcp(1.f + ef[s]);
        #pragma unroll
        for (int s = 0; s < 4; ++s) rg[s] = fast_rcp(1.f + eg[s]);
        #pragma unroll
        for (int s = 0; s < 4; ++s) ro[s] = fast_rcp(1.f + eo[s]);
        #pragma unroll
        for (int s = 0; s < 4; ++s) {
            float tg = fmaf(-2.f, rg[s], 1.f);       // tanh(g)
            float pp = ri[s] * tg;                    // i*tanh(g)
            c1[s] = fmaf(rf[s], c1[s], pp);           // c = f*c + i*tanh(g)
        }
        float ey[4], ry[4], h[4];
        #pragma unroll
        for (int s = 0; s < 4; ++s) ey[s] = __expf(2.f * c1[s]);
        #pragma unroll
        for (int s = 0; s < 4; ++s) ry[s] = fast_rcp(1.f + ey[s]);
        #pragma unroll
        for (int s = 0; s < 4; ++s) {
            float th = fmaf(-2.f, ry[s], 1.f);        // tanh(c)
            h[s] = ro[s] * th;
        }

        hm   = h[2];                                  // L2 h (valid on w3/q0 lanes)
        sum2 = fmaf(msk, h[2], sum2);
        if (t == 0) {                                 // discard the t==0 L2 garbage step
            if (l2lane) c1[2] = 0.f;
            hm = 0.f; sum2 = 0.f;
        }

        // ---- publish h (dead slots write 0 into pad cols; q0-mixed into zero-weight col 51) ----
        #pragma unroll
        for (int s = 0; s < 4; ++s)
            vA[pn][wch[s]][wrow[s]][wjj[s]] = f2bf(h[s]);

        // ---- x stager: write x_{t+1}, prefetch x_{t+2} ----
        if (ns) {
            const int t2 = (t < T_STEPS - 2) ? t + 2 : T_STEPS - 1;
            #pragma unroll
            for (int i = 0; i < 3; ++i) if (i < ns) {
                vA[pn][0][srow[i]][sj[i]] = f2bf(xr[i]);
                xr[i] = sp[i][(size_t)t2 * IN];
            }
        }

        __syncthreads();
    }

    // ---- final layer-2 step: h1_511 sits in vA[0] chunks 1,2 ----
    if (w == 3) {
        s16x8 bf1 = *(const s16x8*)&vA[0][1][lane][0];
        s16x8 bf2 = *(const s16x8*)&vA[0][2][lane][0];
        f32x4 a = binit[2];
        #pragma unroll
        for (int r = 0; r < 4; ++r) a[r] += wadj[r] * hm;
        a = __builtin_amdgcn_mfma_f32_16x16x32_bf16(wf[2][1], bf1, a, 0, 0, 0);
        a = __builtin_amdgcn_mfma_f32_16x16x32_bf16(wf[2][2], bf2, a, 0, 0, 0);
        if (lane < 16) {
            float si = fast_rcp(1.f + __expf(-a[0]));
            float sf = fast_rcp(1.f + __expf(-a[1]));
            float tg = fmaf(-2.f, fast_rcp(1.f + __expf(2.f * a[2])), 1.f);
            float so = fast_rcp(1.f + __expf(-a[3]));
            float c2 = sf * c1[2] + si * tg;
            float h2 = so * fmaf(-2.f, fast_rcp(1.f + __expf(2.f * c2)), 1.f);
            sum2 += h2;

            // ---- head: (lower, mu, upper, log_var) ----
            float agg = sum2 * (1.0f / 512.0f);
            float mu  = Wmu[0] * agg + bmu[0];
            float lv  = Wlv[0] * agg + blv[0];
            float sg  = __expf(0.5f * lv);
            int bg = bidx * 16 + lane;
            out[bg]             = mu - 1.96f * sg;
            out[B_TOT + bg]     = mu;
            out[2 * B_TOT + bg] = mu + 1.96f * sg;
            out[3 * B_TOT + bg] = lv;
        }
    }
}

extern "C" void kernel_launch(void* const* d_in, const int* in_sizes, int n_in,
                              void* d_out, int out_size, void* d_ws, size_t ws_size,
                              hipStream_t stream) {
    const float* x    = (const float*)d_in[0];
    const float* Wih1 = (const float*)d_in[1];
    const float* Whh1 = (const float*)d_in[2];
    const float* bih1 = (const float*)d_in[3];
    const float* bhh1 = (const float*)d_in[4];
    const float* Wih2 = (const float*)d_in[5];
    const float* Whh2 = (const float*)d_in[6];
    const float* bih2 = (const float*)d_in[7];
    const float* bhh2 = (const float*)d_in[8];
    const float* Wmu  = (const float*)d_in[9];
    const float* bmu  = (const float*)d_in[10];
    const float* Wlv  = (const float*)d_in[11];
    const float* blv  = (const float*)d_in[12];
    float* out = (float*)d_out;

    lstm_fused<<<dim3(B_TOT / 16), dim3(256), 0, stream>>>(
        x, Wih1, Whh1, bih1, bhh1, Wih2, Whh2, bih2, bhh2, Wmu, bmu, Wlv, blv, out);
}